// Round 6
// baseline (171.369 us; speedup 1.0000x reference)
//
#include <hip/hip_runtime.h>
#include <math.h>

// VQ-VAE VectorQuantizer forward (fp16 single-product MFMA, barrier-free K-loop):
//   x: [64,32,32,64] f32 -> N=65536 points, D=64
//   E: [D=64, K=1024] f32 (row-major: E[d*K + k])
// Outputs concatenated flat (float32):
//   quantized_st [N*D] | loss [1] | perplexity [1] | encoding_indices [N] (as float)
//
// Fast scan: dist_fast = ||e_k||^2 + BIAS - 2 f.e_k via MFMA f16 (single
// product: x_f16 * (-2E)_f16, fp32 accumulate; abs err ~<8.5e-3 at 5 sigma).
// A-fragments stream directly from a global fp16 [k][d] image of -2E (L2-hot,
// no LDS staging, no barriers in the K loop). Index packed into low 8
// mantissa bits of the biased distance. Gated points (merged top-2 gap <
// GATE) re-resolved with the round-3-proven exact emulation of the np
// reference's fp32 arithmetic (first-occurrence ties).

typedef __attribute__((ext_vector_type(8))) _Float16 half8v;
typedef __attribute__((ext_vector_type(4))) float float4v;
typedef unsigned short u16;
typedef unsigned int u32;

constexpr int D = 64;
constexpr int K = 1024;
constexpr int NPTS = 65536;
constexpr long QOFF = (long)NPTS * D;  // 4194304
constexpr float BIAS = 24.0f;          // dist+BIAS in ~[3,48]: positive, pack-safe
constexpr float GATE = 2e-2f;          // 2*(fp16 5sigma 7.5e-3 + pack 1e-3) + margin

// ws layout (16B-aligned sections):
constexpr size_t OFF_LOSS = 0;                            // double
constexpr size_t OFF_CNT  = 256;                          // int[1024]
constexpr size_t OFF_EC   = 4352;                         // float[1024] ref-order norms
constexpr size_t OFF_ECB  = 8448;                         // float[1024] norms + BIAS
constexpr size_t OFF_ET   = 12544;                        // float[1024*64] E^T [k][d]
constexpr size_t OFF_H16  = OFF_ET + (size_t)K * D * 4;   // _Float16[1024*64] -2E [k][d]
constexpr size_t WS_ZERO  = 4352;                         // zero loss+counts

__device__ __forceinline__ float med3(float a, float b, float c) {
  return __builtin_amdgcn_fmed3f(a, b, c);
}

// Fused prep: ref-order norms + fp32 transpose + fp16 pack of -2E.
__global__ __launch_bounds__(256) void prep(const float* __restrict__ E,
                                            float* __restrict__ eC,
                                            float* __restrict__ eCb,
                                            float* __restrict__ Et,
                                            _Float16* __restrict__ h16) {
  const int gid = blockIdx.x * 256 + threadIdx.x;  // 16384 threads
  // conv: thread handles d = gid>>8, codes k0..k0+3 (coalesced float4 read)
  const int d = gid >> 8;
  const int k0 = (gid & 255) * 4;
  float4 v = *(const float4*)&E[d * K + k0];
  Et[(size_t)(k0 + 0) * 64 + d] = v.x;
  Et[(size_t)(k0 + 1) * 64 + d] = v.y;
  Et[(size_t)(k0 + 2) * 64 + d] = v.z;
  Et[(size_t)(k0 + 3) * 64 + d] = v.w;
  h16[(size_t)(k0 + 0) * 64 + d] = (_Float16)(-2.0f * v.x);
  h16[(size_t)(k0 + 1) * 64 + d] = (_Float16)(-2.0f * v.y);
  h16[(size_t)(k0 + 2) * 64 + d] = (_Float16)(-2.0f * v.z);
  h16[(size_t)(k0 + 3) * 64 + d] = (_Float16)(-2.0f * v.w);
  // norms: first 1024 threads, one code each, np.sum(E**2, axis=0) order
  // (sequential fp32 over d ascending) — coalesced 256B per iteration.
  if (gid < K) {
    float c = __fmul_rn(E[gid], E[gid]);
#pragma unroll
    for (int dd = 1; dd < D; ++dd) {
      float e = E[dd * K + gid];
      c = __fadd_rn(c, __fmul_rn(e, e));
    }
    eC[gid] = c;
    eCb[gid] = c + BIAS;
  }
}

__global__ __launch_bounds__(256) void vq_main(const float* __restrict__ x,
                                               const float* __restrict__ E,
                                               const _Float16* __restrict__ h16,
                                               const float* __restrict__ eC,
                                               const float* __restrict__ eCb,
                                               const float* __restrict__ Etg,
                                               float* __restrict__ out,
                                               double* __restrict__ lossSum,
                                               int* __restrict__ counts) {
  __shared__ __align__(16) float topbuf[256 * 4];
  __shared__ int bkbuf[128];

  const int tid = threadIdx.x;
  const int w = tid >> 6;        // wave id: owns point-tiles 2w, 2w+1
  const int lane = tid & 63;
  const int col = lane & 15;     // A: code row m; B/C: point col n
  const int quad = lane >> 4;    // A/B: k-group; C: row-group
  const int blockBase = blockIdx.x * 128;
  const float INF = __builtin_inff();

  // ---- phase 1: load + convert x into fp16 B-fragments (registers) ----
  // B[k = s*32 + quad*8 + j][n = col], frag element j <-> d = s*32+quad*8+j.
  half8v Bf[2][2];
#pragma unroll
  for (int pt = 0; pt < 2; ++pt) {
    const float* xp = x + (size_t)(blockBase + w * 32 + pt * 16 + col) * 64;
#pragma unroll
    for (int s = 0; s < 2; ++s) {
      const float4* src = (const float4*)(xp + s * 32 + quad * 8);
      float4 a = src[0], b = src[1];
      half8v hf;
      hf[0] = (_Float16)a.x; hf[1] = (_Float16)a.y;
      hf[2] = (_Float16)a.z; hf[3] = (_Float16)a.w;
      hf[4] = (_Float16)b.x; hf[5] = (_Float16)b.y;
      hf[6] = (_Float16)b.z; hf[7] = (_Float16)b.w;
      Bf[pt][s] = hf;
    }
  }

  // running top-2 of packed biased distances, per point-tile
  float b1[2] = {INF, INF}, b2[2] = {INF, INF};

  // ---- phase 2: barrier-free K loop: 8 chunks x 8 code-tiles of 16 ----
#pragma unroll 2
  for (int ch = 0; ch < 8; ++ch) {
#pragma unroll
    for (int ct = 0; ct < 8; ++ct) {
      const int krow = ch * 128 + ct * 16;
      const _Float16* arow = h16 + (size_t)(krow + col) * 64 + quad * 8;
      half8v A0 = *(const half8v*)arow;          // d = quad*8+j
      half8v A1 = *(const half8v*)(arow + 32);   // d = 32+quad*8+j
      float4v Ci = *(const float4v*)&eCb[krow + quad * 4];  // biased norms
#pragma unroll
      for (int pt = 0; pt < 2; ++pt) {
        float4v C = Ci;
        C = __builtin_amdgcn_mfma_f32_16x16x32_f16(A0, Bf[pt][0], C, 0, 0, 0);
        C = __builtin_amdgcn_mfma_f32_16x16x32_f16(A1, Bf[pt][1], C, 0, 0, 0);
#pragma unroll
        for (int r = 0; r < 4; ++r) {
          // pack local id (ch:3b | ct:3b | r:2b) into low 8 mantissa bits
          u32 u = (__float_as_uint(C[r]) & 0xffffff00u) |
                  (u32)(ch * 32 + ct * 4 + r);
          float v = __uint_as_float(u);
          float pb = b1[pt];
          b1[pt] = fminf(pb, v);
          b2[pt] = med3(pb, b2[pt], v);
        }
      }
    }
  }

  // ---- phase 3: stash per-lane top-2, merge per point, gate + refine ----
  topbuf[tid * 4 + 0] = b1[0];
  topbuf[tid * 4 + 1] = b2[0];
  topbuf[tid * 4 + 2] = b1[1];
  topbuf[tid * 4 + 3] = b2[1];
  __syncthreads();

  if (tid < 128) {  // one thread per point (tid == point-in-block)
    const int mw = tid >> 5, mpt = (tid >> 4) & 1, mcol = tid & 15;
    float cv[8];
    int cq[8];
    float mv0 = INF, mv1 = INF;
    int q0 = 0;
#pragma unroll
    for (int q = 0; q < 4; ++q) {
      int lbase = (mw * 64 + q * 16 + mcol) * 4 + mpt * 2;
#pragma unroll
      for (int j = 0; j < 2; ++j) {
        float v = topbuf[lbase + j];
        cv[q * 2 + j] = v;
        cq[q * 2 + j] = q;
        if (v < mv0) { mv1 = mv0; mv0 = v; q0 = q; }
        else if (v < mv1) { mv1 = v; }
      }
    }
    u32 lb = __float_as_uint(mv0) & 255u;
    int bestk = (int)((lb >> 5) * 128 + ((lb >> 2) & 7) * 16 + q0 * 4 + (lb & 3));

    if (mv1 - mv0 < GATE) {
      // ----- exact emulation of the np reference's fp32 arithmetic -----
      const float* f = x + (size_t)(blockBase + tid) * 64;
      float r8[8];
#pragma unroll
      for (int j = 0; j < 8; ++j) { float fv = f[j]; r8[j] = __fmul_rn(fv, fv); }
#pragma unroll
      for (int i = 8; i < D; i += 8)
#pragma unroll
        for (int j = 0; j < 8; ++j) {
          float fv = f[i + j];
          r8[j] = __fadd_rn(r8[j], __fmul_rn(fv, fv));
        }
      float A = __fadd_rn(__fadd_rn(__fadd_rn(r8[0], r8[1]), __fadd_rn(r8[2], r8[3])),
                          __fadd_rn(__fadd_rn(r8[4], r8[5]), __fadd_rn(r8[6], r8[7])));
      float bd = INF;
      int bkk = K;
#pragma unroll
      for (int c = 0; c < 8; ++c) {
        u32 cb = __float_as_uint(cv[c]) & 255u;
        int k = (int)((cb >> 5) * 128 + ((cb >> 2) & 7) * 16 + cq[c] * 4 + (cb & 3));
        float m = 0.f;  // sequential fp32 fma over d (BLAS k-loop order)
#pragma unroll
        for (int d = 0; d < D; ++d) m = __fmaf_rn(f[d], E[d * K + k], m);
        float dist = __fadd_rn(__fsub_rn(A, __fmul_rn(2.f, m)), eC[k]);
        bool better = (dist < bd) || (dist == bd && k < bkk);
        bd = better ? dist : bd;
        bkk = better ? k : bkk;
      }
      bestk = bkk;
    }

    bkbuf[tid] = bestk;
    out[QOFF + 2 + blockBase + tid] = (float)bestk;  // index (exact as float)
    atomicAdd(&counts[bestk], 1);
  }
  __syncthreads();

  // ---- phase 4: quantized write (gather from Et, coalesced) + loss ----
  const int pp = tid >> 1, half = tid & 1;
  const int bk = bkbuf[pp];
  const float4* et = (const float4*)(Etg + (size_t)bk * 64 + half * 32);
  const float4* xr = (const float4*)(x + (size_t)(blockBase + pp) * 64 + half * 32);
  float4* ov = (float4*)(out + (size_t)(blockBase + pp) * 64 + half * 32);
  float errs = 0.f;
#pragma unroll
  for (int i = 0; i < 8; ++i) {
    float4 qv = et[i];
    float4 xv = xr[i];
    float dx;
    dx = qv.x - xv.x; errs = fmaf(dx, dx, errs);
    dx = qv.y - xv.y; errs = fmaf(dx, dx, errs);
    dx = qv.z - xv.z; errs = fmaf(dx, dx, errs);
    dx = qv.w - xv.w; errs = fmaf(dx, dx, errs);
    ov[i] = qv;
  }
  double de = (double)errs;
#pragma unroll
  for (int off = 32; off > 0; off >>= 1) de += __shfl_down(de, off, 64);
  if (lane == 0) atomicAdd(lossSum, de);
}

__global__ __launch_bounds__(256) void vq_finalize(const double* __restrict__ lossSum,
                                                   const int* __restrict__ counts,
                                                   float* __restrict__ out) {
  __shared__ double sh[256];
  double ent = 0.0;
  for (int k = threadIdx.x; k < K; k += 256) {
    double pp = (double)counts[k] / (double)NPTS;
    ent += pp * log(pp + 1e-10);
  }
  sh[threadIdx.x] = ent;
  __syncthreads();
  for (int s = 128; s > 0; s >>= 1) {
    if (threadIdx.x < s) sh[threadIdx.x] += sh[threadIdx.x + s];
    __syncthreads();
  }
  if (threadIdx.x == 0) {
    // loss = q_latent + 0.25 * e_latent = 1.25 * mean((q - x)^2)
    out[QOFF + 0] = (float)(1.25 * (*lossSum) / (double)((long)NPTS * D));
    out[QOFF + 1] = (float)exp(-sh[0]);  // perplexity
  }
}

extern "C" void kernel_launch(void* const* d_in, const int* in_sizes, int n_in,
                              void* d_out, int out_size, void* d_ws, size_t ws_size,
                              hipStream_t stream) {
  const float* x = (const float*)d_in[0];
  const float* E = (const float*)d_in[1];
  float* out = (float*)d_out;

  char* ws = (char*)d_ws;
  double* lossSum = (double*)(ws + OFF_LOSS);
  int* counts = (int*)(ws + OFF_CNT);
  float* eC = (float*)(ws + OFF_EC);
  float* eCb = (float*)(ws + OFF_ECB);
  float* Etg = (float*)(ws + OFF_ET);
  _Float16* h16 = (_Float16*)(ws + OFF_H16);

  // ws is poisoned 0xAA before every timed launch — zero accumulators.
  hipMemsetAsync(d_ws, 0, WS_ZERO, stream);

  prep<<<64, 256, 0, stream>>>(E, eC, eCb, Etg, h16);
  vq_main<<<NPTS / 128, 256, 0, stream>>>(x, E, h16, eC, eCb, Etg, out,
                                          lossSum, counts);
  vq_finalize<<<1, 256, 0, stream>>>(lossSum, counts, out);
}